// Round 1
// baseline (129.148 us; speedup 1.0000x reference)
//
#include <hip/hip_runtime.h>
#include <hip/hip_bf16.h>

#define T_TOKENS 4096
#define F_IN 4096
#define O_OUT 4096
#define NC 68          // 64 mid cols (e*16+r) + 4 router cols
#define SCALE_F 4.0f   // 16 / sqrt(16)

#define PART_ELEMS (4 * T_TOKENS * NC)   // fp32 partials [fb][t][c]

// ---------------------------------------------------------------------------
// Kernel A: P[t, c] = sum_f x[t,f] * W[c,f],  W rows 0..63 = A (viewed [64,4096]),
// rows 64..67 = Wr. Grid = 64 token-blocks * 4 F-chunks. Writes partials.
// ---------------------------------------------------------------------------
__global__ __launch_bounds__(256) void ka_midgemm(const float* __restrict__ x,
                                                  const float* __restrict__ A,
                                                  const float* __restrict__ Wr,
                                                  float* __restrict__ part) {
    __shared__ float xl[64][68];   // [token][k] padded
    __shared__ float wl[80][68];   // [col][k]  rows 68..79 junk (never written out)

    const int tb  = (blockIdx.x & 63) * 64;
    const int fb  = blockIdx.x >> 6;       // 0..3, F chunk of 1024
    const int tid = threadIdx.x;
    const int tg  = tid & 15;              // token group
    const int cg  = tid >> 4;              // col group
    const int t0  = tg * 4;
    const int c0  = cg * 5;

    float acc[4][5];
#pragma unroll
    for (int i = 0; i < 4; ++i)
#pragma unroll
        for (int j = 0; j < 5; ++j) acc[i][j] = 0.f;

    for (int ch = 0; ch < 16; ++ch) {
        const int f0 = fb * 1024 + ch * 64;
        // stage x tile: 64 rows x 64 floats = 1024 float4
#pragma unroll
        for (int i = 0; i < 4; ++i) {
            int lin = tid + i * 256;         // 0..1023
            int row = lin >> 4;
            int c4  = lin & 15;
            *(float4*)&xl[row][c4 * 4] =
                *(const float4*)&x[(size_t)(tb + row) * F_IN + f0 + c4 * 4];
        }
        // stage W tile: 68 rows x 64 floats = 1088 float4
#pragma unroll
        for (int i = 0; i < 5; ++i) {
            int lin = tid + i * 256;
            if (lin < 1088) {
                int row = lin >> 4;
                int c4  = lin & 15;
                const float* src = (row < 64) ? (A + (size_t)row * F_IN)
                                              : (Wr + (size_t)(row - 64) * F_IN);
                *(float4*)&wl[row][c4 * 4] = *(const float4*)&src[f0 + c4 * 4];
            }
        }
        __syncthreads();
#pragma unroll
        for (int k4 = 0; k4 < 16; ++k4) {
            float4 xv[4], wv[5];
#pragma unroll
            for (int i = 0; i < 4; ++i) xv[i] = *(float4*)&xl[t0 + i][k4 * 4];
#pragma unroll
            for (int j = 0; j < 5; ++j) wv[j] = *(float4*)&wl[c0 + j][k4 * 4];
#pragma unroll
            for (int i = 0; i < 4; ++i)
#pragma unroll
                for (int j = 0; j < 5; ++j) {
                    acc[i][j] += xv[i].x * wv[j].x;
                    acc[i][j] += xv[i].y * wv[j].y;
                    acc[i][j] += xv[i].z * wv[j].z;
                    acc[i][j] += xv[i].w * wv[j].w;
                }
        }
        __syncthreads();
    }
#pragma unroll
    for (int i = 0; i < 4; ++i)
#pragma unroll
        for (int j = 0; j < 5; ++j) {
            int c = c0 + j;
            if (c < NC)
                part[(size_t)fb * T_TOKENS * NC + (size_t)(tb + t0 + i) * NC + c] =
                    acc[i][j];
        }
}

// ---------------------------------------------------------------------------
// Kernel A2: reduce 4 F-partials, per-token top-2 softmax gating,
// write mid_w[t, e*16+r] = gate*SCALE*mid. Grid = 64 blocks of 64 tokens.
// ---------------------------------------------------------------------------
__global__ __launch_bounds__(256) void ka2_gate(const float* __restrict__ part,
                                                float* __restrict__ midw) {
    __shared__ float vl[64][68];
    __shared__ float gl[64][4];

    const int tb  = blockIdx.x * 64;
    const int tid = threadIdx.x;
    const int t   = tid >> 2;
    const int p   = tid & 3;

#pragma unroll
    for (int j = 0; j < 17; ++j) {
        int c = p * 17 + j;
        float s = 0.f;
#pragma unroll
        for (int fb = 0; fb < 4; ++fb)
            s += part[(size_t)fb * T_TOKENS * NC + (size_t)(tb + t) * NC + c];
        vl[t][c] = s;
    }
    __syncthreads();
    if (tid < 64) {
        float v[4];
#pragma unroll
        for (int e = 0; e < 4; ++e) v[e] = vl[tid][64 + e];
        // top-1 (lowest index on tie, matches jax top_k)
        int i1 = 0; float m1 = v[0];
#pragma unroll
        for (int e = 1; e < 4; ++e)
            if (v[e] > m1) { m1 = v[e]; i1 = e; }
        // top-2
        int i2 = -1; float m2 = 0.f;
#pragma unroll
        for (int e = 0; e < 4; ++e)
            if (e != i1 && (i2 < 0 || v[e] > m2)) { m2 = v[e]; i2 = e; }
        float ex = __expf(m2 - m1);
        float inv = 1.f / (1.f + ex);
#pragma unroll
        for (int e = 0; e < 4; ++e) gl[tid][e] = 0.f;
        gl[tid][i1] = inv * SCALE_F;
        gl[tid][i2] = ex * inv * SCALE_F;
    }
    __syncthreads();
#pragma unroll
    for (int j = 0; j < 17; ++j) {
        int c = p * 17 + j;
        if (c < 64)
            midw[(size_t)(tb + t) * 64 + c] = vl[t][c] * gl[t][c >> 4];
    }
}

// ---------------------------------------------------------------------------
// Kernel B: out[t, o] = sum_{k=e*16+r} midw[t,k] * B[e,o,r].
// Grid = (T/64) x (O/64) = 4096 blocks, 64x64 tile, K=64.
// ---------------------------------------------------------------------------
__global__ __launch_bounds__(256) void kb_delta(const float* __restrict__ midw,
                                                const float* __restrict__ B,
                                                float* __restrict__ out) {
    __shared__ float ml[64][68];   // [k][t]
    __shared__ float bl[64][68];   // [k][o]

    const int tb  = (blockIdx.x & 63) * 64;
    const int ob  = (blockIdx.x >> 6) * 64;
    const int tid = threadIdx.x;

#pragma unroll
    for (int i = 0; i < 16; ++i) {
        int lin = tid + i * 256;      // 0..4095
        int t = lin >> 6, k = lin & 63;
        ml[k][t] = midw[(size_t)(tb + t) * 64 + k];
    }
#pragma unroll
    for (int i = 0; i < 16; ++i) {
        int lin = tid + i * 256;
        int o = lin >> 6, k = lin & 63;
        int e = k >> 4, r = k & 15;
        bl[k][o] = B[(size_t)e * O_OUT * 16 + (size_t)(ob + o) * 16 + r];
    }
    __syncthreads();

    const int og = tid & 15, tg = tid >> 4;
    const int o0 = og * 4, t0 = tg * 4;
    float acc[4][4];
#pragma unroll
    for (int i = 0; i < 4; ++i)
#pragma unroll
        for (int j = 0; j < 4; ++j) acc[i][j] = 0.f;

#pragma unroll
    for (int k = 0; k < 64; ++k) {
        float4 mv = *(float4*)&ml[k][t0];
        float4 bv = *(float4*)&bl[k][o0];
        acc[0][0] += mv.x * bv.x; acc[0][1] += mv.x * bv.y;
        acc[0][2] += mv.x * bv.z; acc[0][3] += mv.x * bv.w;
        acc[1][0] += mv.y * bv.x; acc[1][1] += mv.y * bv.y;
        acc[1][2] += mv.y * bv.z; acc[1][3] += mv.y * bv.w;
        acc[2][0] += mv.z * bv.x; acc[2][1] += mv.z * bv.y;
        acc[2][2] += mv.z * bv.z; acc[2][3] += mv.z * bv.w;
        acc[3][0] += mv.w * bv.x; acc[3][1] += mv.w * bv.y;
        acc[3][2] += mv.w * bv.z; acc[3][3] += mv.w * bv.w;
    }
#pragma unroll
    for (int i = 0; i < 4; ++i) {
        float4 r4 = make_float4(acc[i][0], acc[i][1], acc[i][2], acc[i][3]);
        *(float4*)&out[(size_t)(tb + t0 + i) * O_OUT + ob + o0] = r4;
    }
}

extern "C" void kernel_launch(void* const* d_in, const int* in_sizes, int n_in,
                              void* d_out, int out_size, void* d_ws, size_t ws_size,
                              hipStream_t stream) {
    const float* x  = (const float*)d_in[0];
    const float* A  = (const float*)d_in[1];
    const float* B  = (const float*)d_in[2];
    const float* Wr = (const float*)d_in[3];
    float* out  = (float*)d_out;
    float* part = (float*)d_ws;
    float* midw = part + PART_ELEMS;

    ka_midgemm<<<256, 256, 0, stream>>>(x, A, Wr, part);
    ka2_gate<<<64, 256, 0, stream>>>(part, midw);
    kb_delta<<<4096, 256, 0, stream>>>(midw, B, out);
}

// Round 2
// 53.546 us; speedup vs baseline: 2.4119x; 2.4119x over previous
//
#include <hip/hip_runtime.h>

#define T_TOKENS 4096
#define F_IN 4096
#define O_OUT 4096
#define SCALE_F 4.0f   // 16 / sqrt(16)

typedef __attribute__((ext_vector_type(8))) short bf16x8;
typedef __attribute__((ext_vector_type(4))) float f32x4;

// ws element offsets (as ushort elements unless noted)
#define WBM_E   0          // A packed:  [4096/8][64][8]  = 262144 bf16
#define WRB_E   262144     // Wr packed: [4096/8][16][8]  =  65536 bf16 (cols 0-3 hi, 4-7 lo, 8-15 zero)
#define BB_E    327680     // B packed:  [64/8][4096][8]  = 262144 bf16
#define PART_F  294912     // fp32 offset (byte 1179648): partial [2][4096][80] fp32
#define MIDW_E  1900544    // byte 3801088: midw [4096][64] bf16

__device__ __forceinline__ unsigned short f2bf(float f) {
    unsigned u = __float_as_uint(f);
    unsigned r = (u + 0x7fffu + ((u >> 16) & 1u)) >> 16;
    return (unsigned short)r;
}
__device__ __forceinline__ float bf2f(unsigned short h) {
    return __uint_as_float(((unsigned)h) << 16);
}

// ---------------------------------------------------------------------------
// Pre-pack: A -> wbm, Wr -> wrb (hi/lo split), B -> bb, all in MFMA B-operand
// fragment order [k>>3][col][k&7]. 589824 items.
// ---------------------------------------------------------------------------
__global__ __launch_bounds__(256) void kprep(const float* __restrict__ A,
                                             const float* __restrict__ B,
                                             const float* __restrict__ Wr,
                                             unsigned short* __restrict__ ws) {
    int idx = blockIdx.x * 256 + threadIdx.x;
    if (idx < 262144) {                      // wbm: A[c][k], c = e*16+r
        int ki = idx & 7, c = (idx >> 3) & 63, kb = idx >> 9;
        int k = kb * 8 + ki;
        ws[WBM_E + idx] = f2bf(A[(size_t)c * F_IN + k]);
    } else if (idx < 327680) {               // wrb
        int j = idx - 262144;
        int ki = j & 7, cc = (j >> 3) & 15, kb = j >> 7;
        int k = kb * 8 + ki;
        unsigned short outv = 0;
        if (cc < 4) {
            outv = f2bf(Wr[(size_t)cc * F_IN + k]);
        } else if (cc < 8) {
            float v = Wr[(size_t)(cc - 4) * F_IN + k];
            unsigned short hi = f2bf(v);
            outv = f2bf(v - bf2f(hi));
        }
        ws[WRB_E + j] = outv;
    } else if (idx < 589824) {               // bb: B[e][o][r], k = e*16+r
        int j = idx - 327680;
        int ki = j & 7, o = (j >> 3) & 4095, kb = j >> 15;
        int k = kb * 8 + ki;
        int e = k >> 4, r = k & 15;
        ws[BB_E + j] = f2bf(B[((size_t)e * O_OUT + o) * 16 + r]);
    }
}

// ---------------------------------------------------------------------------
// Kernel A: per wave: 16 tokens x 512 K-chunk, 6 MFMAs/step (4 mid tiles +
// 2 router tiles for the hi/lo precision split). Cross-wave LDS reduce,
// write fp32 partial [kh][t][80] (cols 0-63 mid, 64-71 tile4, 72-79 tile5).
// Grid: 512 blocks (256 token-groups x 2 K-halves) x 256 threads.
// ---------------------------------------------------------------------------
__global__ __launch_bounds__(256) void ka_mfma(const float* __restrict__ x,
                                               const unsigned short* __restrict__ wpack,
                                               float* __restrict__ partial) {
    const int tid = threadIdx.x;
    const int w = tid >> 6, l = tid & 63;
    const int lm = l & 15, lk = l >> 4;
    const int tg = (int)blockIdx.x >> 1, kh = (int)blockIdx.x & 1;
    const int tb = tg * 16;
    const int kbase = kh * 2048 + w * 512;

    const bf16x8* wbm8 = (const bf16x8*)(wpack + WBM_E);   // [k>>3]*64 + col
    const bf16x8* wrb8 = (const bf16x8*)(wpack + WRB_E);   // [k>>3]*16 + col

    f32x4 am0 = {0.f,0.f,0.f,0.f}, am1 = am0, am2 = am0, am3 = am0;
    f32x4 ar0 = am0, ar1 = am0;

    const float* xrow = x + (size_t)(tb + lm) * F_IN;

#pragma unroll 4
    for (int s = 0; s < 16; ++s) {
        const int kc = kbase + s * 32 + lk * 8;
        float4 xa = *(const float4*)(xrow + kc);
        float4 xb = *(const float4*)(xrow + kc + 4);
        float f[8] = {xa.x, xa.y, xa.z, xa.w, xb.x, xb.y, xb.z, xb.w};
        bf16x8 xhi, xlo;
#pragma unroll
        for (int j = 0; j < 8; ++j) {
            unsigned short h = f2bf(f[j]);
            xhi[j] = (short)h;
            xlo[j] = (short)f2bf(f[j] - bf2f(h));
        }
        const int kb8 = kc >> 3;
        bf16x8 w0 = wbm8[kb8 * 64 +  0 + lm];
        bf16x8 w1 = wbm8[kb8 * 64 + 16 + lm];
        bf16x8 w2 = wbm8[kb8 * 64 + 32 + lm];
        bf16x8 w3 = wbm8[kb8 * 64 + 48 + lm];
        bf16x8 wr = wrb8[kb8 * 16 + lm];
        am0 = __builtin_amdgcn_mfma_f32_16x16x32_bf16(xhi, w0, am0, 0, 0, 0);
        am1 = __builtin_amdgcn_mfma_f32_16x16x32_bf16(xhi, w1, am1, 0, 0, 0);
        am2 = __builtin_amdgcn_mfma_f32_16x16x32_bf16(xhi, w2, am2, 0, 0, 0);
        am3 = __builtin_amdgcn_mfma_f32_16x16x32_bf16(xhi, w3, am3, 0, 0, 0);
        ar0 = __builtin_amdgcn_mfma_f32_16x16x32_bf16(xhi, wr, ar0, 0, 0, 0);
        ar1 = __builtin_amdgcn_mfma_f32_16x16x32_bf16(xlo, wr, ar1, 0, 0, 0);
    }

    __shared__ float red[4][6][64][4];   // 24 KB
    *(f32x4*)&red[w][0][l][0] = am0;
    *(f32x4*)&red[w][1][l][0] = am1;
    *(f32x4*)&red[w][2][l][0] = am2;
    *(f32x4*)&red[w][3][l][0] = am3;
    *(f32x4*)&red[w][4][l][0] = ar0;
    *(f32x4*)&red[w][5][l][0] = ar1;
    __syncthreads();

#pragma unroll
    for (int it = 0; it < 6; ++it) {
        int j = tid + it * 256;
        int tile = j >> 8, rem = j & 255, rl = rem >> 2, q = rem & 3;
        float s = red[0][tile][rl][q] + red[1][tile][rl][q] +
                  red[2][tile][rl][q] + red[3][tile][rl][q];
        int token = ((rl >> 4) << 2) + q, c = rl & 15;
        int col;
        if (tile < 4)      col = tile * 16 + c;
        else if (c < 8)    col = (tile == 4 ? 64 : 72) + c;
        else               col = -1;
        if (col >= 0)
            partial[(size_t)kh * T_TOKENS * 80 + (size_t)(tb + token) * 80 + col] = s;
    }
}

// ---------------------------------------------------------------------------
// Kernel A2: combine 2 K-half partials, fp32 top-2 softmax gate, fold
// gate*SCALE, emit midw bf16 [4096][64]. Thread per token, grid 16x256.
// ---------------------------------------------------------------------------
__global__ __launch_bounds__(256) void ka2(const float* __restrict__ partial,
                                           unsigned short* __restrict__ midw) {
    int t = blockIdx.x * 256 + threadIdx.x;
    const float* p0 = partial + (size_t)t * 80;
    const float* p1 = partial + (size_t)T_TOKENS * 80 + (size_t)t * 80;
    float lg[4];
#pragma unroll
    for (int e = 0; e < 4; ++e)
        lg[e] = p0[64 + e] + p0[68 + e] + p0[72 + e] + p0[76 + e]
              + p1[64 + e] + p1[68 + e] + p1[72 + e] + p1[76 + e];
    int i1 = 0; float m1 = lg[0];
#pragma unroll
    for (int e = 1; e < 4; ++e)
        if (lg[e] > m1) { m1 = lg[e]; i1 = e; }
    int i2 = -1; float m2 = 0.f;
#pragma unroll
    for (int e = 0; e < 4; ++e)
        if (e != i1 && (i2 < 0 || lg[e] > m2)) { m2 = lg[e]; i2 = e; }
    float ex = __expf(m2 - m1);
    float inv = 1.f / (1.f + ex);
    float g[4] = {0.f, 0.f, 0.f, 0.f};
    g[i1] = inv * SCALE_F;
    g[i2] = ex * inv * SCALE_F;
#pragma unroll
    for (int c = 0; c < 64; ++c)
        midw[(size_t)t * 64 + c] = f2bf((p0[c] + p1[c]) * g[c >> 4]);
}

// ---------------------------------------------------------------------------
// Kernel B: out[t,o] = midw[t,:] . Bcat[:,o] via MFMA, K=64 (2 steps).
// Block: 64 tokens x 64 cols (wave per 16-token subtile). Grid 4096.
// ---------------------------------------------------------------------------
__global__ __launch_bounds__(256) void kb_mfma(const unsigned short* __restrict__ midw,
                                               const unsigned short* __restrict__ bbp,
                                               float* __restrict__ out) {
    const int tid = threadIdx.x;
    const int w = tid >> 6, l = tid & 63;
    const int lm = l & 15, lk = l >> 4;
    const int tb = ((int)blockIdx.x & 63) * 64 + w * 16;
    const int ob = ((int)blockIdx.x >> 6) * 64;
    const bf16x8* m8 = (const bf16x8*)midw;   // t*8 + (k>>3)
    const bf16x8* b8 = (const bf16x8*)bbp;    // (k>>3)*4096 + o

    f32x4 acc0 = {0.f,0.f,0.f,0.f}, acc1 = acc0, acc2 = acc0, acc3 = acc0;
#pragma unroll
    for (int k0 = 0; k0 < 64; k0 += 32) {
        const int kb8 = (k0 >> 3) + lk;
        bf16x8 ma = m8[(size_t)(tb + lm) * 8 + kb8];
        bf16x8 b0 = b8[(size_t)kb8 * 4096 + ob +  0 + lm];
        bf16x8 b1 = b8[(size_t)kb8 * 4096 + ob + 16 + lm];
        bf16x8 b2 = b8[(size_t)kb8 * 4096 + ob + 32 + lm];
        bf16x8 b3 = b8[(size_t)kb8 * 4096 + ob + 48 + lm];
        acc0 = __builtin_amdgcn_mfma_f32_16x16x32_bf16(ma, b0, acc0, 0, 0, 0);
        acc1 = __builtin_amdgcn_mfma_f32_16x16x32_bf16(ma, b1, acc1, 0, 0, 0);
        acc2 = __builtin_amdgcn_mfma_f32_16x16x32_bf16(ma, b2, acc2, 0, 0, 0);
        acc3 = __builtin_amdgcn_mfma_f32_16x16x32_bf16(ma, b3, acc3, 0, 0, 0);
    }
#pragma unroll
    for (int q = 0; q < 4; ++q) {
        const size_t row = (size_t)(tb + lk * 4 + q) * O_OUT + ob + lm;
        out[row +  0] = acc0[q];
        out[row + 16] = acc1[q];
        out[row + 32] = acc2[q];
        out[row + 48] = acc3[q];
    }
}

extern "C" void kernel_launch(void* const* d_in, const int* in_sizes, int n_in,
                              void* d_out, int out_size, void* d_ws, size_t ws_size,
                              hipStream_t stream) {
    const float* x  = (const float*)d_in[0];
    const float* A  = (const float*)d_in[1];
    const float* B  = (const float*)d_in[2];
    const float* Wr = (const float*)d_in[3];
    float* out = (float*)d_out;

    unsigned short* wsu = (unsigned short*)d_ws;
    float* partial = (float*)d_ws + PART_F;
    unsigned short* midw = wsu + MIDW_E;

    kprep<<<2304, 256, 0, stream>>>(A, B, Wr, wsu);
    ka_mfma<<<512, 256, 0, stream>>>(x, wsu, partial);
    ka2<<<16, 256, 0, stream>>>(partial, midw);
    kb_mfma<<<4096, 256, 0, stream>>>(midw, wsu + BB_E, out);
}